// Round 2
// baseline (916.913 us; speedup 1.0000x reference)
//
#include <hip/hip_runtime.h>
#include <hip/hip_bf16.h>

// Problem constants
constexpr int HD    = 768;     // hidden
constexpr int K1    = 1536;    // 2*hidden
constexpr int VOCAB = 30522;
constexpr int VPAD  = 30592;   // 239 * 128
constexpr int MROWS = 4096;    // B*S = 8*512
constexpr int NINST = 10;

typedef __attribute__((ext_vector_type(8))) short short8;
typedef __attribute__((ext_vector_type(4))) float f32x4;

__device__ __forceinline__ unsigned short f2bf(float f) {
    unsigned int x = __float_as_uint(f);
    x += 0x7fffu + ((x >> 16) & 1u);     // round-to-nearest-even
    return (unsigned short)(x >> 16);
}

// ---------------------------------------------------------------------------
// Convert f32 -> bf16 (vectorized float4 -> 4x bf16), zero-pad past valid4.
// ---------------------------------------------------------------------------
__global__ __launch_bounds__(256) void convert_bf16_kernel(
    const float* __restrict__ src, unsigned short* __restrict__ dst,
    long long valid4, long long total4)
{
    for (long long i = (long long)blockIdx.x * 256 + threadIdx.x; i < total4;
         i += (long long)gridDim.x * 256) {
        uint2 o; o.x = 0u; o.y = 0u;
        if (i < valid4) {
            float4 v = ((const float4*)src)[i];
            o.x = (unsigned)f2bf(v.x) | ((unsigned)f2bf(v.y) << 16);
            o.y = (unsigned)f2bf(v.z) | ((unsigned)f2bf(v.w) << 16);
        }
        ((uint2*)dst)[i] = o;
    }
}

// ---------------------------------------------------------------------------
// Gather positional row + concat with feature row -> X (MROWS x K1) bf16.
// ---------------------------------------------------------------------------
__global__ __launch_bounds__(256) void build_x_kernel(
    const float* __restrict__ feat, const int* __restrict__ labels,
    unsigned short* __restrict__ X)
{
    int m = blockIdx.x;              // 0..4095
    int b = m >> 9;
    int lab = labels[m];
    if (lab == -100) lab = 0;
    lab = lab < 0 ? 0 : (lab > NINST - 1 ? NINST - 1 : lab);
    const float4* prow = (const float4*)(feat + ((size_t)b * 512 + lab) * HD);
    const float4* frow = (const float4*)(feat + (size_t)m * HD);
    unsigned short* xr = X + (size_t)m * K1;
    for (int c = threadIdx.x; c < 384; c += 256) {
        float4 v = (c < 192) ? prow[c] : frow[c - 192];
        uint2 o;
        o.x = (unsigned)f2bf(v.x) | ((unsigned)f2bf(v.y) << 16);
        o.y = (unsigned)f2bf(v.z) | ((unsigned)f2bf(v.w) << 16);
        *(uint2*)(xr + c * 4) = o;
    }
}

// ---------------------------------------------------------------------------
// LayerNorm over rows of y (MROWS x HD f32) -> hidden bf16.
// ---------------------------------------------------------------------------
__global__ __launch_bounds__(256) void ln_kernel(
    const float* __restrict__ y, const float* __restrict__ lnw,
    const float* __restrict__ lnb, unsigned short* __restrict__ hidden)
{
    int r = blockIdx.x;
    int tid = threadIdx.x;
    const float* row = y + (size_t)r * HD;
    float v[3];
    float s = 0.f, sq = 0.f;
#pragma unroll
    for (int i = 0; i < 3; ++i) {
        v[i] = row[tid + i * 256];
        s += v[i];
        sq += v[i] * v[i];
    }
    for (int o = 32; o > 0; o >>= 1) {
        s += __shfl_xor(s, o);
        sq += __shfl_xor(sq, o);
    }
    __shared__ float red[8];
    int w = tid >> 6, lane = tid & 63;
    if (lane == 0) { red[w] = s; red[w + 4] = sq; }
    __syncthreads();
    __shared__ float stats[2];
    if (tid == 0) {
        float S = red[0] + red[1] + red[2] + red[3];
        float Q = red[4] + red[5] + red[6] + red[7];
        float mu = S * (1.f / HD);
        float var = Q * (1.f / HD) - mu * mu;
        stats[0] = mu;
        stats[1] = rsqrtf(var + 1e-12f);
    }
    __syncthreads();
    float mu = stats[0], rs = stats[1];
#pragma unroll
    for (int i = 0; i < 3; ++i) {
        int h = tid + i * 256;
        float o = (v[i] - mu) * rs * lnw[h] + lnb[h];
        hidden[(size_t)r * HD + h] = f2bf(o);
    }
}

// ---------------------------------------------------------------------------
// NT GEMM: C[M,N] = A[M,K] * Bt[N,K]^T  (A,Bt bf16 row-major; acc f32)
// 128x128 tile, 4 waves (2x2), 16x16x32 bf16 MFMA, global_load_lds width 16.
// EPI 0: +bias, exact GELU, store f32 (GEMM1).  EPI 1: +bias, store f32 (GEMM2).
// Grid must be (32 m-tiles) * (ntn n-tiles), divisible by 8 for XCD swizzle.
// ---------------------------------------------------------------------------
#define ASYNC16(SRC, DST) __builtin_amdgcn_global_load_lds( \
    (const __attribute__((address_space(1))) void*)(SRC),   \
    (__attribute__((address_space(3))) void*)(DST), 16, 0, 0)

template<int KTILES, int EPI>
__global__ __launch_bounds__(256, 2) void gemm_bt(
    const unsigned short* __restrict__ A, const unsigned short* __restrict__ Bt,
    const float* __restrict__ bias, float* __restrict__ C,
    int lda, int ldb, int ldc, int nvalid)
{
    __shared__ __align__(16) unsigned short smA[128 * 32];
    __shared__ __align__(16) unsigned short smB[128 * 32];

    const int tid  = threadIdx.x;
    const int lane = tid & 63;
    const int w    = tid >> 6;
    const int wr   = (w >> 1) * 64;   // wave row offset in tile
    const int wc   = (w & 1) * 64;    // wave col offset in tile

    // XCD-aware swizzle (gridDim.x % 8 == 0), m-tile fastest within an XCD chunk
    const int nwg = gridDim.x;
    const int cpx = nwg >> 3;
    const int swz = ((int)blockIdx.x & 7) * cpx + ((int)blockIdx.x >> 3);
    const int m0 = (swz & 31) * 128;
    const int n0 = (swz >> 5) * 128;

    const int srow = tid >> 2;            // staging row
    const int sc8  = (tid & 3) << 3;      // staging col (8 bf16 = 16B chunk)
    const int fr   = lane & 15;           // fragment row within 16
    const int fk   = (lane >> 4) << 3;    // fragment k offset (0,8,16,24)

    f32x4 acc[4][4];
#pragma unroll
    for (int i = 0; i < 4; ++i)
#pragma unroll
        for (int j = 0; j < 4; ++j)
            acc[i][j] = f32x4{0.f, 0.f, 0.f, 0.f};

    for (int kt = 0; kt < KTILES; ++kt) {
        const int k0 = kt * 32;
        __syncthreads();
        {
            const unsigned short* a0 = A + (size_t)(m0 + srow) * lda + k0 + sc8;
            const unsigned short* a1 = A + (size_t)(m0 + 64 + srow) * lda + k0 + sc8;
            const unsigned short* b0 = Bt + (size_t)(n0 + srow) * ldb + k0 + sc8;
            const unsigned short* b1 = Bt + (size_t)(n0 + 64 + srow) * ldb + k0 + sc8;
            ASYNC16(a0, smA + tid * 8);
            ASYNC16(a1, smA + 2048 + tid * 8);
            ASYNC16(b0, smB + tid * 8);
            ASYNC16(b1, smB + 2048 + tid * 8);
        }
        __syncthreads();   // drains vmcnt: async LDS writes complete

        short8 af[4], bfr[4];
#pragma unroll
        for (int i = 0; i < 4; ++i)
            af[i] = *(const short8*)(smA + (wr + i * 16 + fr) * 32 + fk);
#pragma unroll
        for (int j = 0; j < 4; ++j)
            bfr[j] = *(const short8*)(smB + (wc + j * 16 + fr) * 32 + fk);
#pragma unroll
        for (int i = 0; i < 4; ++i)
#pragma unroll
            for (int j = 0; j < 4; ++j)
                acc[i][j] = __builtin_amdgcn_mfma_f32_16x16x32_bf16(
                    af[i], bfr[j], acc[i][j], 0, 0, 0);
    }

    // Epilogue. C/D layout: col = lane&15, row = (lane>>4)*4 + r  [m89]
    const int coln = lane & 15;
    const int rb   = (lane >> 4) << 2;
#pragma unroll
    for (int i = 0; i < 4; ++i) {
        const int mrow = m0 + wr + i * 16 + rb;
#pragma unroll
        for (int j = 0; j < 4; ++j) {
            const int ncol = n0 + wc + j * 16 + coln;
            if (ncol < nvalid) {
                const float bv = bias[ncol];
#pragma unroll
                for (int r = 0; r < 4; ++r) {
                    float v = acc[i][j][r] + bv;
                    if (EPI == 0)
                        v = 0.5f * v * (1.f + erff(v * 0.70710678118654752f));
                    C[(size_t)(mrow + r) * ldc + ncol] = v;
                }
            }
        }
    }
}

// ---------------------------------------------------------------------------
// Launch
// ---------------------------------------------------------------------------
extern "C" void kernel_launch(void* const* d_in, const int* in_sizes, int n_in,
                              void* d_out, int out_size, void* d_ws, size_t ws_size,
                              hipStream_t stream)
{
    const float* features = (const float*)d_in[0];
    const float* dense_w  = (const float*)d_in[1];
    const float* dense_b  = (const float*)d_in[2];
    const float* ln_w     = (const float*)d_in[3];
    const float* ln_b     = (const float*)d_in[4];
    const float* dec_w    = (const float*)d_in[5];
    const float* dec_b    = (const float*)d_in[6];
    const int*   labels   = (const int*)d_in[7];

    char* ws = (char*)d_ws;
    unsigned short* X      = (unsigned short*)(ws);              // 4096*1536*2  = 12582912
    unsigned short* denseW = (unsigned short*)(ws + 12582912);   // 768*1536*2   =  2359296
    float*          y      = (float*)(ws + 14942208);            // 4096*768*4   = 12582912
    unsigned short* hidden = (unsigned short*)(ws + 27525120);   // 4096*768*2   =  6291456
    unsigned short* decW   = (unsigned short*)(ws + 33816576);   // 30592*768*2  = 46989312

    // 1) dec_w -> bf16 (padded to VPAD rows with zeros)
    convert_bf16_kernel<<<2048, 256, 0, stream>>>(
        dec_w, decW, (long long)VOCAB * HD / 4, (long long)VPAD * HD / 4);
    // 2) dense_w -> bf16
    convert_bf16_kernel<<<512, 256, 0, stream>>>(
        dense_w, denseW, (long long)HD * K1 / 4, (long long)HD * K1 / 4);
    // 3) gather + concat -> X bf16
    build_x_kernel<<<MROWS, 256, 0, stream>>>(features, labels, X);
    // 4) GEMM1: y = gelu(X @ dense_w^T + dense_b)   [4096 x 768], grid 32*6=192
    gemm_bt<K1 / 32, 0><<<192, 256, 0, stream>>>(
        X, denseW, dense_b, y, K1, K1, HD, HD);
    // 5) LayerNorm -> hidden bf16
    ln_kernel<<<MROWS, 256, 0, stream>>>(y, ln_w, ln_b, hidden);
    // 6) GEMM2: logits = hidden @ dec_w^T + dec_b   [4096 x 30522], grid 32*239=7648
    gemm_bt<HD / 32, 1><<<7648, 256, 0, stream>>>(
        hidden, decW, dec_b, (float*)d_out, HD, HD, VOCAB, VOCAB);
}

// Round 3
// 881.923 us; speedup vs baseline: 1.0397x; 1.0397x over previous
//
#include <hip/hip_runtime.h>
#include <hip/hip_bf16.h>

// Problem constants
constexpr int HD    = 768;     // hidden
constexpr int K1    = 1536;    // 2*hidden
constexpr int VOCAB = 30522;
constexpr int VPAD2 = 30720;   // 120 * 256  (GEMM2 N padding)
constexpr int MROWS = 4096;    // B*S = 8*512
constexpr int NINST = 10;

typedef __attribute__((ext_vector_type(8))) short short8;
typedef __attribute__((ext_vector_type(4))) float f32x4;
typedef unsigned short u16;

__device__ __forceinline__ u16 f2bf(float f) {
    unsigned int x = __float_as_uint(f);
    x += 0x7fffu + ((x >> 16) & 1u);     // round-to-nearest-even
    return (u16)(x >> 16);
}

#define ASYNC16(SRC, DST) __builtin_amdgcn_global_load_lds( \
    (const __attribute__((address_space(1))) void*)(SRC),   \
    (__attribute__((address_space(3))) void*)(DST), 16, 0, 0)

// ---------------------------------------------------------------------------
// Convert f32 -> bf16 (vectorized float4 -> 4x bf16), zero-pad past valid4.
// ---------------------------------------------------------------------------
__global__ __launch_bounds__(256) void convert_bf16_kernel(
    const float* __restrict__ src, u16* __restrict__ dst,
    long long valid4, long long total4)
{
    for (long long i = (long long)blockIdx.x * 256 + threadIdx.x; i < total4;
         i += (long long)gridDim.x * 256) {
        uint2 o; o.x = 0u; o.y = 0u;
        if (i < valid4) {
            float4 v = ((const float4*)src)[i];
            o.x = (unsigned)f2bf(v.x) | ((unsigned)f2bf(v.y) << 16);
            o.y = (unsigned)f2bf(v.z) | ((unsigned)f2bf(v.w) << 16);
        }
        ((uint2*)dst)[i] = o;
    }
}

// ---------------------------------------------------------------------------
// Gather positional row + concat with feature row -> X (MROWS x K1) bf16.
// ---------------------------------------------------------------------------
__global__ __launch_bounds__(256) void build_x_kernel(
    const float* __restrict__ feat, const int* __restrict__ labels,
    u16* __restrict__ X)
{
    int m = blockIdx.x;              // 0..4095
    int b = m >> 9;
    int lab = labels[m];
    if (lab == -100) lab = 0;
    lab = lab < 0 ? 0 : (lab > NINST - 1 ? NINST - 1 : lab);
    const float4* prow = (const float4*)(feat + ((size_t)b * 512 + lab) * HD);
    const float4* frow = (const float4*)(feat + (size_t)m * HD);
    u16* xr = X + (size_t)m * K1;
    for (int c = threadIdx.x; c < 384; c += 256) {
        float4 v = (c < 192) ? prow[c] : frow[c - 192];
        uint2 o;
        o.x = (unsigned)f2bf(v.x) | ((unsigned)f2bf(v.y) << 16);
        o.y = (unsigned)f2bf(v.z) | ((unsigned)f2bf(v.w) << 16);
        *(uint2*)(xr + c * 4) = o;
    }
}

// ---------------------------------------------------------------------------
// LayerNorm over rows of y (MROWS x HD f32) -> hidden bf16.
// ---------------------------------------------------------------------------
__global__ __launch_bounds__(256) void ln_kernel(
    const float* __restrict__ y, const float* __restrict__ lnw,
    const float* __restrict__ lnb, u16* __restrict__ hidden)
{
    int r = blockIdx.x;
    int tid = threadIdx.x;
    const float* row = y + (size_t)r * HD;
    float v[3];
    float s = 0.f, sq = 0.f;
#pragma unroll
    for (int i = 0; i < 3; ++i) {
        v[i] = row[tid + i * 256];
        s += v[i];
        sq += v[i] * v[i];
    }
    for (int o = 32; o > 0; o >>= 1) {
        s += __shfl_xor(s, o);
        sq += __shfl_xor(sq, o);
    }
    __shared__ float red[8];
    int w = tid >> 6, lane = tid & 63;
    if (lane == 0) { red[w] = s; red[w + 4] = sq; }
    __syncthreads();
    __shared__ float stats[2];
    if (tid == 0) {
        float S = red[0] + red[1] + red[2] + red[3];
        float Q = red[4] + red[5] + red[6] + red[7];
        float mu = S * (1.f / HD);
        float var = Q * (1.f / HD) - mu * mu;
        stats[0] = mu;
        stats[1] = rsqrtf(var + 1e-12f);
    }
    __syncthreads();
    float mu = stats[0], rs = stats[1];
#pragma unroll
    for (int i = 0; i < 3; ++i) {
        int h = tid + i * 256;
        float o = (v[i] - mu) * rs * lnw[h] + lnb[h];
        hidden[(size_t)r * HD + h] = f2bf(o);
    }
}

// ---------------------------------------------------------------------------
// GEMM1 (kept from round 2): NT 128x128 tile, 2-barrier loop.
// ---------------------------------------------------------------------------
template<int KTILES, int EPI>
__global__ __launch_bounds__(256, 2) void gemm_bt(
    const u16* __restrict__ A, const u16* __restrict__ Bt,
    const float* __restrict__ bias, float* __restrict__ C,
    int lda, int ldb, int ldc, int nvalid)
{
    __shared__ __align__(16) u16 smA[128 * 32];
    __shared__ __align__(16) u16 smB[128 * 32];

    const int tid  = threadIdx.x;
    const int lane = tid & 63;
    const int w    = tid >> 6;
    const int wr   = (w >> 1) * 64;
    const int wc   = (w & 1) * 64;

    const int nwg = gridDim.x;
    const int cpx = nwg >> 3;
    const int swz = ((int)blockIdx.x & 7) * cpx + ((int)blockIdx.x >> 3);
    const int m0 = (swz & 31) * 128;
    const int n0 = (swz >> 5) * 128;

    const int srow = tid >> 2;
    const int sc8  = (tid & 3) << 3;
    const int fr   = lane & 15;
    const int fk   = (lane >> 4) << 3;

    f32x4 acc[4][4];
#pragma unroll
    for (int i = 0; i < 4; ++i)
#pragma unroll
        for (int j = 0; j < 4; ++j)
            acc[i][j] = f32x4{0.f, 0.f, 0.f, 0.f};

    for (int kt = 0; kt < KTILES; ++kt) {
        const int k0 = kt * 32;
        __syncthreads();
        {
            const u16* a0 = A + (size_t)(m0 + srow) * lda + k0 + sc8;
            const u16* a1 = A + (size_t)(m0 + 64 + srow) * lda + k0 + sc8;
            const u16* b0 = Bt + (size_t)(n0 + srow) * ldb + k0 + sc8;
            const u16* b1 = Bt + (size_t)(n0 + 64 + srow) * ldb + k0 + sc8;
            ASYNC16(a0, smA + tid * 8);
            ASYNC16(a1, smA + 2048 + tid * 8);
            ASYNC16(b0, smB + tid * 8);
            ASYNC16(b1, smB + 2048 + tid * 8);
        }
        __syncthreads();

        short8 af[4], bfr[4];
#pragma unroll
        for (int i = 0; i < 4; ++i)
            af[i] = *(const short8*)(smA + (wr + i * 16 + fr) * 32 + fk);
#pragma unroll
        for (int j = 0; j < 4; ++j)
            bfr[j] = *(const short8*)(smB + (wc + j * 16 + fr) * 32 + fk);
#pragma unroll
        for (int i = 0; i < 4; ++i)
#pragma unroll
            for (int j = 0; j < 4; ++j)
                acc[i][j] = __builtin_amdgcn_mfma_f32_16x16x32_bf16(
                    af[i], bfr[j], acc[i][j], 0, 0, 0);
    }

    const int coln = lane & 15;
    const int rb   = (lane >> 4) << 2;
#pragma unroll
    for (int i = 0; i < 4; ++i) {
        const int mrow = m0 + wr + i * 16 + rb;
#pragma unroll
        for (int j = 0; j < 4; ++j) {
            const int ncol = n0 + wc + j * 16 + coln;
            if (ncol < nvalid) {
                const float bv = bias[ncol];
#pragma unroll
                for (int r = 0; r < 4; ++r) {
                    float v = acc[i][j][r] + bv;
                    if (EPI == 0)
                        v = 0.5f * v * (1.f + erff(v * 0.70710678118654752f));
                    C[(size_t)(mrow + r) * ldc + ncol] = v;
                }
            }
        }
    }
}

// ---------------------------------------------------------------------------
// GEMM2: 256x256 tile, BK=32, 4-slot LDS pipeline (3 K-tiles lookahead),
// counted vmcnt(8) at K-tile boundaries, XOR-swizzled LDS, setprio MFMA.
// C[4096][30522] = hidden[4096][768] @ decW[30720][768]^T + dec_b
// Grid = 16 * 120 = 1920 blocks, 512 threads (8 waves, 2M x 4N).
// ---------------------------------------------------------------------------
__global__ __launch_bounds__(512, 2) void gemm2_256(
    const u16* __restrict__ A, const u16* __restrict__ Bt,
    const float* __restrict__ bias, float* __restrict__ C)
{
    constexpr int KT = 24;                       // 768 / 32
    __shared__ __align__(16) u16 lds[4][2][8192];  // [slot][A|B][256*32] = 128 KiB

    const int tid  = threadIdx.x;
    const int lane = tid & 63;
    const int w    = tid >> 6;
    const int wr   = w >> 2;          // 0..1  (M half)
    const int wc   = w & 3;           // 0..3  (N quarter)

    const int nwg = gridDim.x;        // 1920
    const int cpx = nwg >> 3;
    const int swz = ((int)blockIdx.x & 7) * cpx + ((int)blockIdx.x >> 3);
    const int m0 = (swz & 15) * 256;  // 16 m-tiles, fastest within XCD chunk
    const int n0 = (swz >> 4) * 256;  // 120 n-tiles

    // staging addressing (src pre-swizzled so LDS content is XOR-swizzled;
    // gload_lds dest must stay linear: base + lane*16B)
    const int srow   = tid >> 2;                // 0..127
    const int schunk = (tid & 3) * 8;           // element chunk 0,8,16,24
    const int sxor   = ((srow & 8) ? 16 : 0) ^ ((srow & 4) ? 8 : 0);
    const int scol   = schunk ^ sxor;
    const u16* aS = A  + (size_t)(m0 + srow) * HD + scol;
    const u16* bS = Bt + (size_t)(n0 + srow) * HD + scol;

    // fragment addressing (same XOR on read side)
    const int fr = lane & 15;
    const int fk = (lane >> 4) * 8;
    const int fx = fk ^ ((fr & 8) ? 16 : 0) ^ ((fr & 4) ? 8 : 0);
    const int wrOff = wr * 128;
    const int wc64  = wc * 64;

    f32x4 acc[8][4];
#pragma unroll
    for (int i = 0; i < 8; ++i)
#pragma unroll
        for (int j = 0; j < 4; ++j)
            acc[i][j] = f32x4{0.f, 0.f, 0.f, 0.f};

    short8 breg[4], areg[4];

#define STAGEH(SLOT, T, J) do {                                              \
        ASYNC16(aS + (size_t)(J) * (128 * HD) + (T) * 32,                    \
                &lds[SLOT][0][(J) * 4096 + tid * 8]);                        \
        ASYNC16(bS + (size_t)(J) * (128 * HD) + (T) * 32,                    \
                &lds[SLOT][1][(J) * 4096 + tid * 8]);                        \
    } while (0)

#define BARRIER() asm volatile("s_barrier" ::: "memory")

#define PHASE_MFMA(IOFF)                                                     \
    asm volatile("s_waitcnt lgkmcnt(0)" ::: "memory");                       \
    __builtin_amdgcn_sched_barrier(0);                                       \
    __builtin_amdgcn_s_setprio(1);                                           \
    _Pragma("unroll")                                                        \
    for (int i = 0; i < 4; ++i)                                              \
        _Pragma("unroll")                                                    \
        for (int j = 0; j < 4; ++j)                                          \
            acc[(IOFF) + i][j] = __builtin_amdgcn_mfma_f32_16x16x32_bf16(    \
                areg[i], breg[j], acc[(IOFF) + i][j], 0, 0, 0);              \
    __builtin_amdgcn_s_setprio(0);

    // TILE body: 2 phases; stages K-tile t+3 into slot (t+3)&3 (= slot of
    // t-1, whose reads completed before the boundary barrier -> no WAR).
#define TILE(T, STG, CLOSE_ASM, FINAL_BAR) do {                              \
        const int s_  = (T) & 3;                                             \
        const u16* ab_ = &lds[s_][0][0];                                     \
        const u16* bb_ = &lds[s_][1][0];                                     \
        /* phase 0: B frags + A quad 0 */                                    \
        _Pragma("unroll")                                                    \
        for (int j = 0; j < 4; ++j)                                          \
            breg[j] = *(const short8*)(bb_ + (wc64 + j * 16 + fr) * 32 + fx);\
        _Pragma("unroll")                                                    \
        for (int i = 0; i < 4; ++i)                                          \
            areg[i] = *(const short8*)(ab_ + (wrOff + i * 16 + fr) * 32 + fx);\
        if (STG) STAGEH((T + 3) & 3, (T) + 3, 0);                            \
        BARRIER();                                                           \
        PHASE_MFMA(0)                                                        \
        BARRIER();                                                           \
        /* phase 1: A quad 1, reuse B frags */                               \
        _Pragma("unroll")                                                    \
        for (int i = 0; i < 4; ++i)                                          \
            areg[i] = *(const short8*)(ab_ + (wrOff + 64 + i * 16 + fr) * 32 + fx);\
        if (STG) STAGEH((T + 3) & 3, (T) + 3, 1);                            \
        BARRIER();                                                           \
        PHASE_MFMA(4)                                                        \
        CLOSE_ASM;                                                           \
        if (FINAL_BAR) BARRIER();                                            \
    } while (0)

    // Prologue: stage K-tiles 0,1,2 (12 loads/wave); retire tile 0 (vmcnt(8)).
    STAGEH(0, 0, 0); STAGEH(0, 0, 1);
    STAGEH(1, 1, 0); STAGEH(1, 1, 1);
    STAGEH(2, 2, 0); STAGEH(2, 2, 1);
    asm volatile("s_waitcnt vmcnt(8)" ::: "memory");
    BARRIER();

    // Main loop: tiles 0..KT-4, steady-state vmcnt(8) boundary.
    for (int t = 0; t < KT - 3; ++t)
        TILE(t, true, asm volatile("s_waitcnt vmcnt(8)" ::: "memory"), true);
    // Peeled tail: no staging; outstanding loads 8 -> 4 -> 0.
    TILE(KT - 3, false, asm volatile("s_waitcnt vmcnt(4)" ::: "memory"), true);
    TILE(KT - 2, false, asm volatile("s_waitcnt vmcnt(0)" ::: "memory"), true);
    TILE(KT - 1, false, , false);

#undef TILE
#undef PHASE_MFMA
#undef BARRIER
#undef STAGEH

    // Epilogue: C/D layout col = lane&15, row = (lane>>4)*4 + r
    const int coln = lane & 15;
    const int rb   = (lane >> 4) << 2;
#pragma unroll
    for (int i = 0; i < 8; ++i) {
        const int mrow = m0 + wrOff + i * 16 + rb;
#pragma unroll
        for (int j = 0; j < 4; ++j) {
            const int ncol = n0 + wc64 + j * 16 + coln;
            if (ncol < VOCAB) {
                const float bv = bias[ncol];
#pragma unroll
                for (int r = 0; r < 4; ++r)
                    C[(size_t)(mrow + r) * VOCAB + ncol] = acc[i][j][r] + bv;
            }
        }
    }
}

// ---------------------------------------------------------------------------
// Launch
// ---------------------------------------------------------------------------
extern "C" void kernel_launch(void* const* d_in, const int* in_sizes, int n_in,
                              void* d_out, int out_size, void* d_ws, size_t ws_size,
                              hipStream_t stream)
{
    const float* features = (const float*)d_in[0];
    const float* dense_w  = (const float*)d_in[1];
    const float* dense_b  = (const float*)d_in[2];
    const float* ln_w     = (const float*)d_in[3];
    const float* ln_b     = (const float*)d_in[4];
    const float* dec_w    = (const float*)d_in[5];
    const float* dec_b    = (const float*)d_in[6];
    const int*   labels   = (const int*)d_in[7];

    char* ws = (char*)d_ws;
    u16*   X      = (u16*)(ws);                  // [0, 12582912)
    u16*   hidden = (u16*)(ws);                  // overlaps X (X dead when LN runs)
    u16*   denseW = (u16*)(ws + 12582912);       // [12582912, 14942208)
    float* y      = (float*)(ws + 14942208);     // [14942208, 27525120)
    u16*   decW   = (u16*)(ws + 27525120);       // [27525120, 74711040) 30720x768

    // 1) dec_w -> bf16 (padded to VPAD2 rows with zeros)
    convert_bf16_kernel<<<2048, 256, 0, stream>>>(
        dec_w, decW, (long long)VOCAB * HD / 4, (long long)VPAD2 * HD / 4);
    // 2) dense_w -> bf16
    convert_bf16_kernel<<<512, 256, 0, stream>>>(
        dense_w, denseW, (long long)HD * K1 / 4, (long long)HD * K1 / 4);
    // 3) gather + concat -> X bf16
    build_x_kernel<<<MROWS, 256, 0, stream>>>(features, labels, X);
    // 4) GEMM1: y = gelu(X @ dense_w^T + dense_b)   [4096 x 768], grid 32*6
    gemm_bt<K1 / 32, 0><<<192, 256, 0, stream>>>(
        X, denseW, dense_b, y, K1, K1, HD, HD);
    // 5) LayerNorm -> hidden bf16 (overwrites X region; X is dead)
    ln_kernel<<<MROWS, 256, 0, stream>>>(y, ln_w, ln_b, hidden);
    // 6) GEMM2: logits = hidden @ dec_w^T + dec_b   [4096 x 30522]
    gemm2_256<<<1920, 512, 0, stream>>>(hidden, decW, dec_b, (float*)d_out);
}